// Round 8
// baseline (431.023 us; speedup 1.0000x reference)
//
#include <hip/hip_runtime.h>
#include <hip/hip_bf16.h>

#define NN 50000
#define NE 800000
#define LEAKY 0.25f
#define SCAN_NB ((NN + 255) / 256)   // 196

typedef __attribute__((ext_vector_type(8))) short bf16x8;
typedef __attribute__((ext_vector_type(8))) ushort u16x8;
typedef __attribute__((ext_vector_type(4))) float f32x4;
typedef unsigned long long ull;

static __device__ __forceinline__ ushort f2bf(float f) {
    union { __hip_bfloat16 h; ushort u; } cv;
    cv.h = __float2bfloat16(f);
    return cv.u;
}
static __device__ __forceinline__ float bf2f(ushort u) {
    union { unsigned u; float f; } cv;
    cv.u = ((unsigned)u) << 16;
    return cv.f;
}

// ---------------- casts ----------------
__global__ void cast_bf16_x8(const float4* __restrict__ in, u16x8* __restrict__ out, int n8) {
    int i = blockIdx.x * blockDim.x + threadIdx.x;
    if (i >= n8) return;
    float4 v0 = in[i * 2];
    float4 v1 = in[i * 2 + 1];
    u16x8 o;
    o[0] = f2bf(v0.x); o[1] = f2bf(v0.y); o[2] = f2bf(v0.z); o[3] = f2bf(v0.w);
    o[4] = f2bf(v1.x); o[5] = f2bf(v1.y); o[6] = f2bf(v1.z); o[7] = f2bf(v1.w);
    out[i] = o;
}

__global__ void cast_transpose_w(const float* __restrict__ W, ushort* __restrict__ Wt, int K, int N) {
    int idx = blockIdx.x * blockDim.x + threadIdx.x;
    if (idx >= K * N) return;
    int k = idx / N, n = idx % N;
    Wt[n * K + k] = f2bf(W[idx]);
}

// ---------------- bf16 MFMA GEMM: C = A @ Bt^T, C written in SLICED layout ----------------
// C layout: [N/SF][M][SF]  (feature-slice-major), SF = 1<<sf_log2
__global__ __launch_bounds__(256) void gemm_bf16(
    const ushort* __restrict__ A, const ushort* __restrict__ Bt,
    ushort* __restrict__ C, int M, int N, int K, int sf_log2)
{
    __shared__ ushort As[128 * 32];
    __shared__ ushort Bs[128 * 32];
    const int tid  = threadIdx.x;
    const int lane = tid & 63;
    const int wid  = tid >> 6;
    const int wr = wid >> 1, wc = wid & 1;
    const int m0 = blockIdx.x * 128;
    const int n0 = blockIdx.y * 128;

    int ar1 = m0 + (tid >> 2);      if (ar1 >= M) ar1 = M - 1;
    int ar2 = m0 + 64 + (tid >> 2); if (ar2 >= M) ar2 = M - 1;
    const int br1 = n0 + (tid >> 2);
    const int br2 = br1 + 64;
    const int ccol = (tid & 3) * 8;

    const ushort* gA1 = A + (size_t)ar1 * K + ccol;
    const ushort* gA2 = A + (size_t)ar2 * K + ccol;
    const ushort* gB1 = Bt + (size_t)br1 * K + ccol;
    const ushort* gB2 = Bt + (size_t)br2 * K + ccol;

    char* ldsA = (char*)As + wid * 1024;
    char* ldsB = (char*)Bs + wid * 1024;

    const int fr = lane & 15;
    const int fq = lane >> 4;

    const ushort* fragA = As + (wr * 64 + fr) * 32 + fq * 8;
    const ushort* fragB = Bs + (wc * 64 + fr) * 32 + fq * 8;

    f32x4 acc[4][4];
    #pragma unroll
    for (int i = 0; i < 4; ++i)
        #pragma unroll
        for (int j = 0; j < 4; ++j)
            acc[i][j] = {0.f, 0.f, 0.f, 0.f};

    for (int k0 = 0; k0 < K; k0 += 32) {
        __builtin_amdgcn_global_load_lds((const __attribute__((address_space(1))) void*)(gA1 + k0),
                                         (__attribute__((address_space(3))) void*)(ldsA), 16, 0, 0);
        __builtin_amdgcn_global_load_lds((const __attribute__((address_space(1))) void*)(gA2 + k0),
                                         (__attribute__((address_space(3))) void*)(ldsA + 4096), 16, 0, 0);
        __builtin_amdgcn_global_load_lds((const __attribute__((address_space(1))) void*)(gB1 + k0),
                                         (__attribute__((address_space(3))) void*)(ldsB), 16, 0, 0);
        __builtin_amdgcn_global_load_lds((const __attribute__((address_space(1))) void*)(gB2 + k0),
                                         (__attribute__((address_space(3))) void*)(ldsB + 4096), 16, 0, 0);
        __syncthreads();

        bf16x8 a[4], b[4];
        #pragma unroll
        for (int mi = 0; mi < 4; ++mi) a[mi] = *(const bf16x8*)(fragA + mi * 16 * 32);
        #pragma unroll
        for (int ni = 0; ni < 4; ++ni) b[ni] = *(const bf16x8*)(fragB + ni * 16 * 32);
        #pragma unroll
        for (int mi = 0; mi < 4; ++mi)
            #pragma unroll
            for (int ni = 0; ni < 4; ++ni)
                acc[mi][ni] = __builtin_amdgcn_mfma_f32_16x16x32_bf16(a[mi], b[ni], acc[mi][ni], 0, 0, 0);
        __syncthreads();
    }

    const int sf_mask = (1 << sf_log2) - 1;
    #pragma unroll
    for (int mi = 0; mi < 4; ++mi) {
        #pragma unroll
        for (int j = 0; j < 4; ++j) {
            int row = m0 + wr * 64 + mi * 16 + fq * 4 + j;
            if (row >= M) continue;
            #pragma unroll
            for (int ni = 0; ni < 4; ++ni) {
                int colg = n0 + wc * 64 + ni * 16 + fr;
                int sl = colg >> sf_log2;
                int off = colg & sf_mask;
                C[(((size_t)sl * M + row) << sf_log2) + off] = f2bf(acc[mi][ni][j]);
            }
        }
    }
}

// ---------------- CSR construction ----------------
__global__ void hist_rows(const int* __restrict__ row, int* __restrict__ cnt) {
    int e = blockIdx.x * blockDim.x + threadIdx.x;
    if (e < NE) atomicAdd(&cnt[row[e]], 1);
}

__global__ void scan_bsum(const int* __restrict__ cnt, int* __restrict__ bsum) {
    int i = blockIdx.x * 256 + threadIdx.x;
    int v = (i < NN) ? cnt[i] : 0;
    #pragma unroll
    for (int off = 32; off >= 1; off >>= 1) v += __shfl_down(v, off);
    __shared__ int ws[4];
    if ((threadIdx.x & 63) == 0) ws[threadIdx.x >> 6] = v;
    __syncthreads();
    if (threadIdx.x == 0) bsum[blockIdx.x] = ws[0] + ws[1] + ws[2] + ws[3];
}

__global__ void scan_boff(const int* __restrict__ bsum, int* __restrict__ boff,
                          int* __restrict__ rowptr) {
    __shared__ int s[256];
    int t = threadIdx.x;
    int v = (t < SCAN_NB) ? bsum[t] : 0;
    s[t] = v;
    __syncthreads();
    #pragma unroll
    for (int off = 1; off < 256; off <<= 1) {
        int u = (t >= off) ? s[t - off] : 0;
        __syncthreads();
        s[t] += u;
        __syncthreads();
    }
    if (t < SCAN_NB) boff[t] = s[t] - v;
    if (t == 255) rowptr[NN] = s[255];
}

__global__ void scan_write(const int* __restrict__ cnt, const int* __restrict__ boff,
                           int* __restrict__ rowptr, int* __restrict__ rowcur) {
    __shared__ int s[256];
    int b = blockIdx.x;
    int t = threadIdx.x;
    int i = b * 256 + t;
    int v = (i < NN) ? cnt[i] : 0;
    s[t] = v;
    __syncthreads();
    #pragma unroll
    for (int off = 1; off < 256; off <<= 1) {
        int u = (t >= off) ? s[t - off] : 0;
        __syncthreads();
        s[t] += u;
        __syncthreads();
    }
    if (i < NN) {
        int ex = boff[b] + s[t] - v;
        rowptr[i] = ex;
        rowcur[i] = ex;
    }
}

__global__ void scatter_edges(const int* __restrict__ row, const int* __restrict__ col,
                              const float* __restrict__ vals,
                              int* __restrict__ rowcur,
                              ull* __restrict__ epack) {
    int e = blockIdx.x * blockDim.x + threadIdx.x;
    if (e < NE) {
        int p = atomicAdd(&rowcur[row[e]], 1);
        ull pk = ((ull)__float_as_uint(vals[e]) << 32) | (unsigned)col[e];
        epack[p] = pk;
    }
}

// ---------------- SpMM gather, feature-sliced for per-XCD L2 residency ----------------
// support layout: [DIM/SF][NN][SF] bf16. Block bx handles slice (bx & 7).
// Per row: SF/8 lanes, 16B (8 feats) per lane. Output written row-major.
template<int DIM, int SF, bool OUT_BF16>
__global__ __launch_bounds__(256) void spmm_sliced(
    const ushort* __restrict__ support,
    const int* __restrict__ rowptr,
    const ull* __restrict__ epack,
    const float* __restrict__ bias,
    void* __restrict__ out) {
    constexpr int LPS = SF / 8;         // lanes per row-slice (4 or 2)
    constexpr int RPB = 256 / LPS;      // rows per block (64 or 128)
    const int slice = blockIdx.x & 7;   // 8 slices -> XCD round-robin
    const int rb    = blockIdx.x >> 3;
    int r = rb * RPB + threadIdx.x / LPS;
    int lane = threadIdx.x % LPS;
    if (r >= NN) return;
    const ushort* sbase = support + ((size_t)slice * NN) * SF + lane * 8;
    int s = rowptr[r], e = rowptr[r + 1];
    float acc0[8] = {}, acc1[8] = {};
    int i = s;
    for (; i + 3 < e; i += 4) {
        ull p0 = epack[i];
        ull p1 = epack[i + 1];
        ull p2 = epack[i + 2];
        ull p3 = epack[i + 3];
        u16x8 v0 = *(const u16x8*)(sbase + (size_t)(unsigned)p0 * SF);
        u16x8 v1 = *(const u16x8*)(sbase + (size_t)(unsigned)p1 * SF);
        u16x8 v2 = *(const u16x8*)(sbase + (size_t)(unsigned)p2 * SF);
        u16x8 v3 = *(const u16x8*)(sbase + (size_t)(unsigned)p3 * SF);
        float w0 = __uint_as_float((unsigned)(p0 >> 32));
        float w1 = __uint_as_float((unsigned)(p1 >> 32));
        float w2 = __uint_as_float((unsigned)(p2 >> 32));
        float w3 = __uint_as_float((unsigned)(p3 >> 32));
        #pragma unroll
        for (int j = 0; j < 8; ++j) acc0[j] += w0 * bf2f(v0[j]);
        #pragma unroll
        for (int j = 0; j < 8; ++j) acc1[j] += w1 * bf2f(v1[j]);
        #pragma unroll
        for (int j = 0; j < 8; ++j) acc0[j] += w2 * bf2f(v2[j]);
        #pragma unroll
        for (int j = 0; j < 8; ++j) acc1[j] += w3 * bf2f(v3[j]);
    }
    for (; i < e; ++i) {
        ull p0 = epack[i];
        float w0 = __uint_as_float((unsigned)(p0 >> 32));
        u16x8 v0 = *(const u16x8*)(sbase + (size_t)(unsigned)p0 * SF);
        #pragma unroll
        for (int j = 0; j < 8; ++j) acc0[j] += w0 * bf2f(v0[j]);
    }
    const int feat0 = slice * SF + lane * 8;
    const float4 bb0 = *(const float4*)(bias + feat0);
    const float4 bb1 = *(const float4*)(bias + feat0 + 4);
    float acc[8];
    #pragma unroll
    for (int j = 0; j < 8; ++j) acc[j] = acc0[j] + acc1[j];
    acc[0] += bb0.x; acc[1] += bb0.y; acc[2] += bb0.z; acc[3] += bb0.w;
    acc[4] += bb1.x; acc[5] += bb1.y; acc[6] += bb1.z; acc[7] += bb1.w;
    #pragma unroll
    for (int j = 0; j < 8; ++j) acc[j] = (acc[j] >= 0.f) ? acc[j] : LEAKY * acc[j];
    if (OUT_BF16) {
        ushort4 o0, o1;
        o0.x = f2bf(acc[0]); o0.y = f2bf(acc[1]); o0.z = f2bf(acc[2]); o0.w = f2bf(acc[3]);
        o1.x = f2bf(acc[4]); o1.y = f2bf(acc[5]); o1.z = f2bf(acc[6]); o1.w = f2bf(acc[7]);
        ushort* op = (ushort*)out + (size_t)r * DIM + feat0;
        *(ushort4*)op = o0;
        *(ushort4*)(op + 4) = o1;
    } else {
        float* op = (float*)out + (size_t)r * DIM + feat0;
        *(float4*)op = {acc[0], acc[1], acc[2], acc[3]};
        *(float4*)(op + 4) = {acc[4], acc[5], acc[6], acc[7]};
    }
}

extern "C" void kernel_launch(void* const* d_in, const int* in_sizes, int n_in,
                              void* d_out, int out_size, void* d_ws, size_t ws_size,
                              hipStream_t stream) {
    const float* x    = (const float*)d_in[0];
    const int*   row  = (const int*)d_in[1];
    const int*   col  = (const int*)d_in[2];
    const float* vals = (const float*)d_in[3];
    const float* W1 = (const float*)d_in[4];  const float* b1 = (const float*)d_in[5];
    const float* W2 = (const float*)d_in[6];  const float* b2 = (const float*)d_in[7];
    const float* W3 = (const float*)d_in[8];  const float* b3 = (const float*)d_in[9];
    const float* W4 = (const float*)d_in[10]; const float* b4 = (const float*)d_in[11];

    ushort* Xb = (ushort*)d_ws;
    ushort* Hb = Xb;
    ushort* S  = Xb + (size_t)NN * 512;
    ushort* Wt1 = S + (size_t)NN * 256;
    ushort* Wt2 = Wt1 + 512 * 256;
    ushort* Wt3 = Wt2 + 256 * 256;
    ushort* Wt4 = Wt3 + 256 * 128;
    int* cnt    = (int*)(Wt4 + 128 * 128);
    int* rowptr = cnt + NN;
    int* rowcur = rowptr + (NN + 1);
    int* pend   = rowcur + (NN + 1);
    ull* epack  = (ull*)pend;
    int* bsum   = (int*)(epack + NE);
    int* boff   = bsum + SCAN_NB;
    float* out  = (float*)d_out;

    // ---- casts ----
    {
        int n8 = NN * 512 / 8;
        cast_bf16_x8<<<(n8 + 255) / 256, 256, 0, stream>>>((const float4*)x, (u16x8*)Xb, n8);
        cast_transpose_w<<<(512 * 256 + 255) / 256, 256, 0, stream>>>(W1, Wt1, 512, 256);
        cast_transpose_w<<<(256 * 256 + 255) / 256, 256, 0, stream>>>(W2, Wt2, 256, 256);
        cast_transpose_w<<<(256 * 128 + 255) / 256, 256, 0, stream>>>(W3, Wt3, 256, 128);
        cast_transpose_w<<<(128 * 128 + 255) / 256, 256, 0, stream>>>(W4, Wt4, 128, 128);
    }

    // ---- build CSR ----
    hipMemsetAsync(cnt, 0, NN * sizeof(int), stream);
    hist_rows<<<(NE + 255) / 256, 256, 0, stream>>>(row, cnt);
    scan_bsum<<<SCAN_NB, 256, 0, stream>>>(cnt, bsum);
    scan_boff<<<1, 256, 0, stream>>>(bsum, boff, rowptr);
    scan_write<<<SCAN_NB, 256, 0, stream>>>(cnt, boff, rowptr, rowcur);
    scatter_edges<<<(NE + 255) / 256, 256, 0, stream>>>(row, col, vals, rowcur, epack);

    const int MT = (NN + 127) / 128;  // 391
    const int G256 = ((NN + 63) / 64) * 8;    // 782*8 = 6256 blocks (slice in low 3 bits)
    const int G128 = ((NN + 127) / 128) * 8;  // 391*8 = 3128

    // layer 1: [50000,512] @ [512,256]   (sf_log2=5 -> 8 slices of 32)
    gemm_bf16<<<dim3(MT, 2), 256, 0, stream>>>(Xb, Wt1, S, NN, 256, 512, 5);
    spmm_sliced<256, 32, true><<<G256, 256, 0, stream>>>(S, rowptr, epack, b1, Hb);
    // layer 2
    gemm_bf16<<<dim3(MT, 2), 256, 0, stream>>>(Hb, Wt2, S, NN, 256, 256, 5);
    spmm_sliced<256, 32, true><<<G256, 256, 0, stream>>>(S, rowptr, epack, b2, Hb);
    // layer 3   (sf_log2=4 -> 8 slices of 16)
    gemm_bf16<<<dim3(MT, 1), 256, 0, stream>>>(Hb, Wt3, S, NN, 128, 256, 4);
    spmm_sliced<128, 16, true><<<G128, 256, 0, stream>>>(S, rowptr, epack, b3, Hb);
    // layer 4
    gemm_bf16<<<dim3(MT, 1), 256, 0, stream>>>(Hb, Wt4, S, NN, 128, 128, 4);
    spmm_sliced<128, 16, false><<<G128, 256, 0, stream>>>(S, rowptr, epack, b4, out);
}

// Round 9
// 397.836 us; speedup vs baseline: 1.0834x; 1.0834x over previous
//
#include <hip/hip_runtime.h>
#include <hip/hip_bf16.h>

#define NN 50000
#define NE 800000
#define LEAKY 0.25f
#define SCAN_NB ((NN + 255) / 256)   // 196

typedef __attribute__((ext_vector_type(8))) short bf16x8;
typedef __attribute__((ext_vector_type(8))) ushort u16x8;
typedef __attribute__((ext_vector_type(4))) float f32x4;
typedef unsigned long long ull;

static __device__ __forceinline__ ushort f2bf(float f) {
    union { __hip_bfloat16 h; ushort u; } cv;
    cv.h = __float2bfloat16(f);
    return cv.u;
}
static __device__ __forceinline__ float bf2f(ushort u) {
    union { unsigned u; float f; } cv;
    cv.u = ((unsigned)u) << 16;
    return cv.f;
}

// ---------------- casts ----------------
__global__ void cast_bf16_x8(const float4* __restrict__ in, u16x8* __restrict__ out, int n8) {
    int i = blockIdx.x * blockDim.x + threadIdx.x;
    if (i >= n8) return;
    float4 v0 = in[i * 2];
    float4 v1 = in[i * 2 + 1];
    u16x8 o;
    o[0] = f2bf(v0.x); o[1] = f2bf(v0.y); o[2] = f2bf(v0.z); o[3] = f2bf(v0.w);
    o[4] = f2bf(v1.x); o[5] = f2bf(v1.y); o[6] = f2bf(v1.z); o[7] = f2bf(v1.w);
    out[i] = o;
}

__global__ void cast_transpose_w(const float* __restrict__ W, ushort* __restrict__ Wt, int K, int N) {
    int idx = blockIdx.x * blockDim.x + threadIdx.x;
    if (idx >= K * N) return;
    int k = idx / N, n = idx % N;
    Wt[n * K + k] = f2bf(W[idx]);
}

// ---------------- bf16 MFMA GEMM: C[M,N] = A[M,K] @ Bt[N,K]^T, full-N tile ----------------
// BN = N (256 or 128). 128xBN tile, 4 waves: wave (wr,wc) computes 64 rows x BN/2 cols.
template<int BN>
__global__ __launch_bounds__(256) void gemm_bf16(
    const ushort* __restrict__ A, const ushort* __restrict__ Bt,
    ushort* __restrict__ C, int M, int K)
{
    constexpr int NI = BN / 32;          // N-frags per wave (8 or 4)
    constexpr int BPASS = BN / 64;       // B staging passes (4 or 2)
    __shared__ ushort As[128 * 32];
    __shared__ ushort Bs[BN * 32];
    const int tid  = threadIdx.x;
    const int lane = tid & 63;
    const int wid  = tid >> 6;
    const int wr = wid >> 1, wc = wid & 1;
    const int m0 = blockIdx.x * 128;

    int ar1 = m0 + (tid >> 2);      if (ar1 >= M) ar1 = M - 1;
    int ar2 = m0 + 64 + (tid >> 2); if (ar2 >= M) ar2 = M - 1;
    const int ccol = (tid & 3) * 8;

    const ushort* gA1 = A + (size_t)ar1 * K + ccol;
    const ushort* gA2 = A + (size_t)ar2 * K + ccol;
    const ushort* gB[BPASS];
    #pragma unroll
    for (int p = 0; p < BPASS; ++p)
        gB[p] = Bt + (size_t)(p * 64 + (tid >> 2)) * K + ccol;

    char* ldsA = (char*)As + wid * 1024;
    char* ldsB = (char*)Bs + wid * 1024;

    const int fr = lane & 15;
    const int fq = lane >> 4;

    const ushort* fragA = As + (wr * 64 + fr) * 32 + fq * 8;
    const ushort* fragB = Bs + (wc * (BN / 2) + fr) * 32 + fq * 8;

    f32x4 acc[4][NI];
    #pragma unroll
    for (int i = 0; i < 4; ++i)
        #pragma unroll
        for (int j = 0; j < NI; ++j)
            acc[i][j] = {0.f, 0.f, 0.f, 0.f};

    for (int k0 = 0; k0 < K; k0 += 32) {
        __builtin_amdgcn_global_load_lds((const __attribute__((address_space(1))) void*)(gA1 + k0),
                                         (__attribute__((address_space(3))) void*)(ldsA), 16, 0, 0);
        __builtin_amdgcn_global_load_lds((const __attribute__((address_space(1))) void*)(gA2 + k0),
                                         (__attribute__((address_space(3))) void*)(ldsA + 4096), 16, 0, 0);
        #pragma unroll
        for (int p = 0; p < BPASS; ++p)
            __builtin_amdgcn_global_load_lds((const __attribute__((address_space(1))) void*)(gB[p] + k0),
                                             (__attribute__((address_space(3))) void*)(ldsB + p * 4096), 16, 0, 0);
        __syncthreads();

        bf16x8 a[4], b[NI];
        #pragma unroll
        for (int mi = 0; mi < 4; ++mi) a[mi] = *(const bf16x8*)(fragA + mi * 16 * 32);
        #pragma unroll
        for (int ni = 0; ni < NI; ++ni) b[ni] = *(const bf16x8*)(fragB + ni * 16 * 32);
        #pragma unroll
        for (int mi = 0; mi < 4; ++mi)
            #pragma unroll
            for (int ni = 0; ni < NI; ++ni)
                acc[mi][ni] = __builtin_amdgcn_mfma_f32_16x16x32_bf16(a[mi], b[ni], acc[mi][ni], 0, 0, 0);
        __syncthreads();
    }

    #pragma unroll
    for (int mi = 0; mi < 4; ++mi) {
        #pragma unroll
        for (int j = 0; j < 4; ++j) {
            int row = m0 + wr * 64 + mi * 16 + fq * 4 + j;
            if (row >= M) continue;
            #pragma unroll
            for (int ni = 0; ni < NI; ++ni) {
                int colg = wc * (BN / 2) + ni * 16 + fr;
                C[(size_t)row * BN + colg] = f2bf(acc[mi][ni][j]);
            }
        }
    }
}

// ---------------- CSR construction ----------------
__global__ void hist_rows(const int* __restrict__ row, int* __restrict__ cnt) {
    int e = blockIdx.x * blockDim.x + threadIdx.x;
    if (e < NE) atomicAdd(&cnt[row[e]], 1);
}

__global__ void scan_bsum(const int* __restrict__ cnt, int* __restrict__ bsum) {
    int i = blockIdx.x * 256 + threadIdx.x;
    int v = (i < NN) ? cnt[i] : 0;
    #pragma unroll
    for (int off = 32; off >= 1; off >>= 1) v += __shfl_down(v, off);
    __shared__ int ws[4];
    if ((threadIdx.x & 63) == 0) ws[threadIdx.x >> 6] = v;
    __syncthreads();
    if (threadIdx.x == 0) bsum[blockIdx.x] = ws[0] + ws[1] + ws[2] + ws[3];
}

__global__ void scan_boff(const int* __restrict__ bsum, int* __restrict__ boff,
                          int* __restrict__ rowptr) {
    __shared__ int s[256];
    int t = threadIdx.x;
    int v = (t < SCAN_NB) ? bsum[t] : 0;
    s[t] = v;
    __syncthreads();
    #pragma unroll
    for (int off = 1; off < 256; off <<= 1) {
        int u = (t >= off) ? s[t - off] : 0;
        __syncthreads();
        s[t] += u;
        __syncthreads();
    }
    if (t < SCAN_NB) boff[t] = s[t] - v;
    if (t == 255) rowptr[NN] = s[255];
}

__global__ void scan_write(const int* __restrict__ cnt, const int* __restrict__ boff,
                           int* __restrict__ rowptr, int* __restrict__ rowcur) {
    __shared__ int s[256];
    int b = blockIdx.x;
    int t = threadIdx.x;
    int i = b * 256 + t;
    int v = (i < NN) ? cnt[i] : 0;
    s[t] = v;
    __syncthreads();
    #pragma unroll
    for (int off = 1; off < 256; off <<= 1) {
        int u = (t >= off) ? s[t - off] : 0;
        __syncthreads();
        s[t] += u;
        __syncthreads();
    }
    if (i < NN) {
        int ex = boff[b] + s[t] - v;
        rowptr[i] = ex;
        rowcur[i] = ex;
    }
}

__global__ void scatter_edges(const int* __restrict__ row, const int* __restrict__ col,
                              const float* __restrict__ vals,
                              int* __restrict__ rowcur,
                              ull* __restrict__ epack) {
    int e = blockIdx.x * blockDim.x + threadIdx.x;
    if (e < NE) {
        int p = atomicAdd(&rowcur[row[e]], 1);
        ull pk = ((ull)__float_as_uint(vals[e]) << 32) | (unsigned)col[e];
        epack[p] = pk;
    }
}

// ---------------- SpMM gather (bf16 support) + bias + leakyReLU fused ----------------
// 4-edge unroll: 4 independent 16B gathers in flight per lane; 2 accumulator sets.
template<int DIM, bool OUT_BF16>
__global__ __launch_bounds__(256) void spmm_gather_bf16(
    const ushort* __restrict__ support,
    const int* __restrict__ rowptr,
    const ull* __restrict__ epack,
    const float* __restrict__ bias,
    void* __restrict__ out) {
    constexpr int LPR = DIM / 8;        // lanes per row (32 or 16)
    constexpr int RPB = 256 / LPR;      // rows per block (8 or 16)
    int r = blockIdx.x * RPB + threadIdx.x / LPR;
    int lane = threadIdx.x % LPR;
    if (r >= NN) return;
    int s = rowptr[r], e = rowptr[r + 1];
    float acc0[8] = {}, acc1[8] = {};
    int i = s;
    for (; i + 3 < e; i += 4) {
        ull p0 = epack[i];
        ull p1 = epack[i + 1];
        ull p2 = epack[i + 2];
        ull p3 = epack[i + 3];
        u16x8 v0 = *((const u16x8*)(support + (size_t)(unsigned)p0 * DIM) + lane);
        u16x8 v1 = *((const u16x8*)(support + (size_t)(unsigned)p1 * DIM) + lane);
        u16x8 v2 = *((const u16x8*)(support + (size_t)(unsigned)p2 * DIM) + lane);
        u16x8 v3 = *((const u16x8*)(support + (size_t)(unsigned)p3 * DIM) + lane);
        float w0 = __uint_as_float((unsigned)(p0 >> 32));
        float w1 = __uint_as_float((unsigned)(p1 >> 32));
        float w2 = __uint_as_float((unsigned)(p2 >> 32));
        float w3 = __uint_as_float((unsigned)(p3 >> 32));
        #pragma unroll
        for (int j = 0; j < 8; ++j) acc0[j] += w0 * bf2f(v0[j]);
        #pragma unroll
        for (int j = 0; j < 8; ++j) acc1[j] += w1 * bf2f(v1[j]);
        #pragma unroll
        for (int j = 0; j < 8; ++j) acc0[j] += w2 * bf2f(v2[j]);
        #pragma unroll
        for (int j = 0; j < 8; ++j) acc1[j] += w3 * bf2f(v3[j]);
    }
    for (; i < e; ++i) {
        ull p0 = epack[i];
        float w0 = __uint_as_float((unsigned)(p0 >> 32));
        u16x8 v0 = *((const u16x8*)(support + (size_t)(unsigned)p0 * DIM) + lane);
        #pragma unroll
        for (int j = 0; j < 8; ++j) acc0[j] += w0 * bf2f(v0[j]);
    }
    const float4 bb0 = ((const float4*)bias)[lane * 2];
    const float4 bb1 = ((const float4*)bias)[lane * 2 + 1];
    float acc[8];
    #pragma unroll
    for (int j = 0; j < 8; ++j) acc[j] = acc0[j] + acc1[j];
    acc[0] += bb0.x; acc[1] += bb0.y; acc[2] += bb0.z; acc[3] += bb0.w;
    acc[4] += bb1.x; acc[5] += bb1.y; acc[6] += bb1.z; acc[7] += bb1.w;
    #pragma unroll
    for (int j = 0; j < 8; ++j) acc[j] = (acc[j] >= 0.f) ? acc[j] : LEAKY * acc[j];
    if (OUT_BF16) {
        ushort4 o0, o1;
        o0.x = f2bf(acc[0]); o0.y = f2bf(acc[1]); o0.z = f2bf(acc[2]); o0.w = f2bf(acc[3]);
        o1.x = f2bf(acc[4]); o1.y = f2bf(acc[5]); o1.z = f2bf(acc[6]); o1.w = f2bf(acc[7]);
        ((ushort4*)out)[(size_t)r * LPR * 2 + lane * 2]     = o0;
        ((ushort4*)out)[(size_t)r * LPR * 2 + lane * 2 + 1] = o1;
    } else {
        float4 f0 = {acc[0], acc[1], acc[2], acc[3]};
        float4 f1 = {acc[4], acc[5], acc[6], acc[7]};
        ((float4*)out)[(size_t)r * LPR * 2 + lane * 2]     = f0;
        ((float4*)out)[(size_t)r * LPR * 2 + lane * 2 + 1] = f1;
    }
}

extern "C" void kernel_launch(void* const* d_in, const int* in_sizes, int n_in,
                              void* d_out, int out_size, void* d_ws, size_t ws_size,
                              hipStream_t stream) {
    const float* x    = (const float*)d_in[0];
    const int*   row  = (const int*)d_in[1];
    const int*   col  = (const int*)d_in[2];
    const float* vals = (const float*)d_in[3];
    const float* W1 = (const float*)d_in[4];  const float* b1 = (const float*)d_in[5];
    const float* W2 = (const float*)d_in[6];  const float* b2 = (const float*)d_in[7];
    const float* W3 = (const float*)d_in[8];  const float* b3 = (const float*)d_in[9];
    const float* W4 = (const float*)d_in[10]; const float* b4 = (const float*)d_in[11];

    ushort* Xb = (ushort*)d_ws;
    ushort* Hb = Xb;
    ushort* S  = Xb + (size_t)NN * 512;
    ushort* Wt1 = S + (size_t)NN * 256;
    ushort* Wt2 = Wt1 + 512 * 256;
    ushort* Wt3 = Wt2 + 256 * 256;
    ushort* Wt4 = Wt3 + 256 * 128;
    int* cnt    = (int*)(Wt4 + 128 * 128);
    int* rowptr = cnt + NN;
    int* rowcur = rowptr + (NN + 1);
    int* pend   = rowcur + (NN + 1);
    ull* epack  = (ull*)pend;
    int* bsum   = (int*)(epack + NE);
    int* boff   = bsum + SCAN_NB;
    float* out  = (float*)d_out;

    // ---- casts ----
    {
        int n8 = NN * 512 / 8;
        cast_bf16_x8<<<(n8 + 255) / 256, 256, 0, stream>>>((const float4*)x, (u16x8*)Xb, n8);
        cast_transpose_w<<<(512 * 256 + 255) / 256, 256, 0, stream>>>(W1, Wt1, 512, 256);
        cast_transpose_w<<<(256 * 256 + 255) / 256, 256, 0, stream>>>(W2, Wt2, 256, 256);
        cast_transpose_w<<<(256 * 128 + 255) / 256, 256, 0, stream>>>(W3, Wt3, 256, 128);
        cast_transpose_w<<<(128 * 128 + 255) / 256, 256, 0, stream>>>(W4, Wt4, 128, 128);
    }

    // ---- build CSR ----
    hipMemsetAsync(cnt, 0, NN * sizeof(int), stream);
    hist_rows<<<(NE + 255) / 256, 256, 0, stream>>>(row, cnt);
    scan_bsum<<<SCAN_NB, 256, 0, stream>>>(cnt, bsum);
    scan_boff<<<1, 256, 0, stream>>>(bsum, boff, rowptr);
    scan_write<<<SCAN_NB, 256, 0, stream>>>(cnt, boff, rowptr, rowcur);
    scatter_edges<<<(NE + 255) / 256, 256, 0, stream>>>(row, col, vals, rowcur, epack);

    const int MT = (NN + 127) / 128;  // 391

    // layer 1: [50000,512] @ [512,256]
    gemm_bf16<256><<<MT, 256, 0, stream>>>(Xb, Wt1, S, NN, 512);
    spmm_gather_bf16<256, true><<<(NN + 7) / 8, 256, 0, stream>>>(S, rowptr, epack, b1, Hb);
    // layer 2: [50000,256] @ [256,256]
    gemm_bf16<256><<<MT, 256, 0, stream>>>(Hb, Wt2, S, NN, 256);
    spmm_gather_bf16<256, true><<<(NN + 7) / 8, 256, 0, stream>>>(S, rowptr, epack, b2, Hb);
    // layer 3: [50000,256] @ [256,128]
    gemm_bf16<128><<<MT, 256, 0, stream>>>(Hb, Wt3, S, NN, 256);
    spmm_gather_bf16<128, true><<<(NN + 15) / 16, 256, 0, stream>>>(S, rowptr, epack, b3, Hb);
    // layer 4: [50000,128] @ [128,128]
    gemm_bf16<128><<<MT, 256, 0, stream>>>(Hb, Wt4, S, NN, 128);
    spmm_gather_bf16<128, false><<<(NN + 15) / 16, 256, 0, stream>>>(S, rowptr, epack, b4, out);
}

// Round 10
// 378.204 us; speedup vs baseline: 1.1397x; 1.0519x over previous
//
#include <hip/hip_runtime.h>
#include <hip/hip_bf16.h>

#define NN 50000
#define NE 800000
#define LEAKY 0.25f
#define SCAN_NB ((NN + 255) / 256)   // 196

typedef __attribute__((ext_vector_type(8))) short bf16x8;
typedef __attribute__((ext_vector_type(8))) ushort u16x8;
typedef __attribute__((ext_vector_type(4))) float f32x4;
typedef unsigned long long ull;

static __device__ __forceinline__ ushort f2bf(float f) {
    union { __hip_bfloat16 h; ushort u; } cv;
    cv.h = __float2bfloat16(f);
    return cv.u;
}
static __device__ __forceinline__ float bf2f(ushort u) {
    union { unsigned u; float f; } cv;
    cv.u = ((unsigned)u) << 16;
    return cv.f;
}

// ---------------- casts ----------------
__global__ void cast_bf16_x8(const float4* __restrict__ in, u16x8* __restrict__ out, int n8) {
    int i = blockIdx.x * blockDim.x + threadIdx.x;
    if (i >= n8) return;
    float4 v0 = in[i * 2];
    float4 v1 = in[i * 2 + 1];
    u16x8 o;
    o[0] = f2bf(v0.x); o[1] = f2bf(v0.y); o[2] = f2bf(v0.z); o[3] = f2bf(v0.w);
    o[4] = f2bf(v1.x); o[5] = f2bf(v1.y); o[6] = f2bf(v1.z); o[7] = f2bf(v1.w);
    out[i] = o;
}

__global__ void cast_transpose_w(const float* __restrict__ W, ushort* __restrict__ Wt, int K, int N) {
    int idx = blockIdx.x * blockDim.x + threadIdx.x;
    if (idx >= K * N) return;
    int k = idx / N, n = idx % N;
    Wt[n * K + k] = f2bf(W[idx]);
}

// ---------------- bf16 MFMA GEMM: C[M,BN] = A[M,K] @ Bt[BN,K]^T, full-N, BM=64 ----------------
// Grid = ceil(M/64) blocks of 256 threads (4 waves, 2x2). Wave computes 32 x BN/2.
template<int BN>
__global__ __launch_bounds__(256) void gemm_bf16(
    const ushort* __restrict__ A, const ushort* __restrict__ Bt,
    ushort* __restrict__ C, int M, int K)
{
    constexpr int NI = BN / 32;          // N-frags per wave (8 or 4)
    constexpr int BPASS = BN / 64;       // B staging passes (4 or 2)
    __shared__ ushort As[64 * 32];
    __shared__ ushort Bs[BN * 32];
    const int tid  = threadIdx.x;
    const int lane = tid & 63;
    const int wid  = tid >> 6;
    const int wr = wid >> 1, wc = wid & 1;
    const int m0 = blockIdx.x * 64;

    int ar = m0 + (tid >> 2); if (ar >= M) ar = M - 1;
    const int ccol = (tid & 3) * 8;

    const ushort* gA = A + (size_t)ar * K + ccol;
    const ushort* gB[BPASS];
    #pragma unroll
    for (int p = 0; p < BPASS; ++p)
        gB[p] = Bt + (size_t)(p * 64 + (tid >> 2)) * K + ccol;

    char* ldsA = (char*)As + wid * 1024;
    char* ldsB = (char*)Bs + wid * 1024;

    const int fr = lane & 15;
    const int fq = lane >> 4;

    const ushort* fragA = As + (wr * 32 + fr) * 32 + fq * 8;
    const ushort* fragB = Bs + (wc * (BN / 2) + fr) * 32 + fq * 8;

    f32x4 acc[2][NI];
    #pragma unroll
    for (int i = 0; i < 2; ++i)
        #pragma unroll
        for (int j = 0; j < NI; ++j)
            acc[i][j] = {0.f, 0.f, 0.f, 0.f};

    for (int k0 = 0; k0 < K; k0 += 32) {
        __builtin_amdgcn_global_load_lds((const __attribute__((address_space(1))) void*)(gA + k0),
                                         (__attribute__((address_space(3))) void*)(ldsA), 16, 0, 0);
        #pragma unroll
        for (int p = 0; p < BPASS; ++p)
            __builtin_amdgcn_global_load_lds((const __attribute__((address_space(1))) void*)(gB[p] + k0),
                                             (__attribute__((address_space(3))) void*)(ldsB + p * 4096), 16, 0, 0);
        __syncthreads();

        bf16x8 a[2], b[NI];
        #pragma unroll
        for (int mi = 0; mi < 2; ++mi) a[mi] = *(const bf16x8*)(fragA + mi * 16 * 32);
        #pragma unroll
        for (int ni = 0; ni < NI; ++ni) b[ni] = *(const bf16x8*)(fragB + ni * 16 * 32);
        #pragma unroll
        for (int mi = 0; mi < 2; ++mi)
            #pragma unroll
            for (int ni = 0; ni < NI; ++ni)
                acc[mi][ni] = __builtin_amdgcn_mfma_f32_16x16x32_bf16(a[mi], b[ni], acc[mi][ni], 0, 0, 0);
        __syncthreads();
    }

    #pragma unroll
    for (int mi = 0; mi < 2; ++mi) {
        #pragma unroll
        for (int j = 0; j < 4; ++j) {
            int row = m0 + wr * 32 + mi * 16 + fq * 4 + j;
            if (row >= M) continue;
            #pragma unroll
            for (int ni = 0; ni < NI; ++ni) {
                int colg = wc * (BN / 2) + ni * 16 + fr;
                C[(size_t)row * BN + colg] = f2bf(acc[mi][ni][j]);
            }
        }
    }
}

// ---------------- CSR construction ----------------
__global__ void hist_rows(const int* __restrict__ row, int* __restrict__ cnt) {
    int e = blockIdx.x * blockDim.x + threadIdx.x;
    if (e < NE) atomicAdd(&cnt[row[e]], 1);
}

__global__ void scan_bsum(const int* __restrict__ cnt, int* __restrict__ bsum) {
    int i = blockIdx.x * 256 + threadIdx.x;
    int v = (i < NN) ? cnt[i] : 0;
    #pragma unroll
    for (int off = 32; off >= 1; off >>= 1) v += __shfl_down(v, off);
    __shared__ int ws[4];
    if ((threadIdx.x & 63) == 0) ws[threadIdx.x >> 6] = v;
    __syncthreads();
    if (threadIdx.x == 0) bsum[blockIdx.x] = ws[0] + ws[1] + ws[2] + ws[3];
}

__global__ void scan_boff(const int* __restrict__ bsum, int* __restrict__ boff,
                          int* __restrict__ rowptr) {
    __shared__ int s[256];
    int t = threadIdx.x;
    int v = (t < SCAN_NB) ? bsum[t] : 0;
    s[t] = v;
    __syncthreads();
    #pragma unroll
    for (int off = 1; off < 256; off <<= 1) {
        int u = (t >= off) ? s[t - off] : 0;
        __syncthreads();
        s[t] += u;
        __syncthreads();
    }
    if (t < SCAN_NB) boff[t] = s[t] - v;
    if (t == 255) rowptr[NN] = s[255];
}

__global__ void scan_write(const int* __restrict__ cnt, const int* __restrict__ boff,
                           int* __restrict__ rowptr, int* __restrict__ rowcur) {
    __shared__ int s[256];
    int b = blockIdx.x;
    int t = threadIdx.x;
    int i = b * 256 + t;
    int v = (i < NN) ? cnt[i] : 0;
    s[t] = v;
    __syncthreads();
    #pragma unroll
    for (int off = 1; off < 256; off <<= 1) {
        int u = (t >= off) ? s[t - off] : 0;
        __syncthreads();
        s[t] += u;
        __syncthreads();
    }
    if (i < NN) {
        int ex = boff[b] + s[t] - v;
        rowptr[i] = ex;
        rowcur[i] = ex;
    }
}

__global__ void scatter_edges(const int* __restrict__ row, const int* __restrict__ col,
                              const float* __restrict__ vals,
                              int* __restrict__ rowcur,
                              ull* __restrict__ epack) {
    int e = blockIdx.x * blockDim.x + threadIdx.x;
    if (e < NE) {
        int p = atomicAdd(&rowcur[row[e]], 1);
        ull pk = ((ull)__float_as_uint(vals[e]) << 32) | (unsigned)col[e];
        epack[p] = pk;
    }
}

// ---------------- SpMM gather (bf16 support) + bias + leakyReLU fused ----------------
template<int DIM, bool OUT_BF16>
__global__ __launch_bounds__(256) void spmm_gather_bf16(
    const ushort* __restrict__ support,
    const int* __restrict__ rowptr,
    const ull* __restrict__ epack,
    const float* __restrict__ bias,
    void* __restrict__ out) {
    constexpr int LPR = DIM / 8;        // lanes per row (32 or 16)
    constexpr int RPB = 256 / LPR;      // rows per block (8 or 16)
    int r = blockIdx.x * RPB + threadIdx.x / LPR;
    int lane = threadIdx.x % LPR;
    if (r >= NN) return;
    int s = rowptr[r], e = rowptr[r + 1];
    float acc0[8] = {}, acc1[8] = {};
    int i = s;
    for (; i + 3 < e; i += 4) {
        ull p0 = epack[i];
        ull p1 = epack[i + 1];
        ull p2 = epack[i + 2];
        ull p3 = epack[i + 3];
        u16x8 v0 = *((const u16x8*)(support + (size_t)(unsigned)p0 * DIM) + lane);
        u16x8 v1 = *((const u16x8*)(support + (size_t)(unsigned)p1 * DIM) + lane);
        u16x8 v2 = *((const u16x8*)(support + (size_t)(unsigned)p2 * DIM) + lane);
        u16x8 v3 = *((const u16x8*)(support + (size_t)(unsigned)p3 * DIM) + lane);
        float w0 = __uint_as_float((unsigned)(p0 >> 32));
        float w1 = __uint_as_float((unsigned)(p1 >> 32));
        float w2 = __uint_as_float((unsigned)(p2 >> 32));
        float w3 = __uint_as_float((unsigned)(p3 >> 32));
        #pragma unroll
        for (int j = 0; j < 8; ++j) acc0[j] += w0 * bf2f(v0[j]);
        #pragma unroll
        for (int j = 0; j < 8; ++j) acc1[j] += w1 * bf2f(v1[j]);
        #pragma unroll
        for (int j = 0; j < 8; ++j) acc0[j] += w2 * bf2f(v2[j]);
        #pragma unroll
        for (int j = 0; j < 8; ++j) acc1[j] += w3 * bf2f(v3[j]);
    }
    for (; i < e; ++i) {
        ull p0 = epack[i];
        float w0 = __uint_as_float((unsigned)(p0 >> 32));
        u16x8 v0 = *((const u16x8*)(support + (size_t)(unsigned)p0 * DIM) + lane);
        #pragma unroll
        for (int j = 0; j < 8; ++j) acc0[j] += w0 * bf2f(v0[j]);
    }
    const float4 bb0 = ((const float4*)bias)[lane * 2];
    const float4 bb1 = ((const float4*)bias)[lane * 2 + 1];
    float acc[8];
    #pragma unroll
    for (int j = 0; j < 8; ++j) acc[j] = acc0[j] + acc1[j];
    acc[0] += bb0.x; acc[1] += bb0.y; acc[2] += bb0.z; acc[3] += bb0.w;
    acc[4] += bb1.x; acc[5] += bb1.y; acc[6] += bb1.z; acc[7] += bb1.w;
    #pragma unroll
    for (int j = 0; j < 8; ++j) acc[j] = (acc[j] >= 0.f) ? acc[j] : LEAKY * acc[j];
    if (OUT_BF16) {
        ushort4 o0, o1;
        o0.x = f2bf(acc[0]); o0.y = f2bf(acc[1]); o0.z = f2bf(acc[2]); o0.w = f2bf(acc[3]);
        o1.x = f2bf(acc[4]); o1.y = f2bf(acc[5]); o1.z = f2bf(acc[6]); o1.w = f2bf(acc[7]);
        ((ushort4*)out)[(size_t)r * LPR * 2 + lane * 2]     = o0;
        ((ushort4*)out)[(size_t)r * LPR * 2 + lane * 2 + 1] = o1;
    } else {
        float4 f0 = {acc[0], acc[1], acc[2], acc[3]};
        float4 f1 = {acc[4], acc[5], acc[6], acc[7]};
        ((float4*)out)[(size_t)r * LPR * 2 + lane * 2]     = f0;
        ((float4*)out)[(size_t)r * LPR * 2 + lane * 2 + 1] = f1;
    }
}

extern "C" void kernel_launch(void* const* d_in, const int* in_sizes, int n_in,
                              void* d_out, int out_size, void* d_ws, size_t ws_size,
                              hipStream_t stream) {
    const float* x    = (const float*)d_in[0];
    const int*   row  = (const int*)d_in[1];
    const int*   col  = (const int*)d_in[2];
    const float* vals = (const float*)d_in[3];
    const float* W1 = (const float*)d_in[4];  const float* b1 = (const float*)d_in[5];
    const float* W2 = (const float*)d_in[6];  const float* b2 = (const float*)d_in[7];
    const float* W3 = (const float*)d_in[8];  const float* b3 = (const float*)d_in[9];
    const float* W4 = (const float*)d_in[10]; const float* b4 = (const float*)d_in[11];

    ushort* Xb = (ushort*)d_ws;
    ushort* Hb = Xb;
    ushort* S  = Xb + (size_t)NN * 512;
    ushort* Wt1 = S + (size_t)NN * 256;
    ushort* Wt2 = Wt1 + 512 * 256;
    ushort* Wt3 = Wt2 + 256 * 256;
    ushort* Wt4 = Wt3 + 256 * 128;
    int* cnt    = (int*)(Wt4 + 128 * 128);
    int* rowptr = cnt + NN;
    int* rowcur = rowptr + (NN + 1);
    int* pend   = rowcur + (NN + 1);
    ull* epack  = (ull*)pend;
    int* bsum   = (int*)(epack + NE);
    int* boff   = bsum + SCAN_NB;
    float* out  = (float*)d_out;

    // ---- casts ----
    {
        int n8 = NN * 512 / 8;
        cast_bf16_x8<<<(n8 + 255) / 256, 256, 0, stream>>>((const float4*)x, (u16x8*)Xb, n8);
        cast_transpose_w<<<(512 * 256 + 255) / 256, 256, 0, stream>>>(W1, Wt1, 512, 256);
        cast_transpose_w<<<(256 * 256 + 255) / 256, 256, 0, stream>>>(W2, Wt2, 256, 256);
        cast_transpose_w<<<(256 * 128 + 255) / 256, 256, 0, stream>>>(W3, Wt3, 256, 128);
        cast_transpose_w<<<(128 * 128 + 255) / 256, 256, 0, stream>>>(W4, Wt4, 128, 128);
    }

    // ---- build CSR ----
    hipMemsetAsync(cnt, 0, NN * sizeof(int), stream);
    hist_rows<<<(NE + 255) / 256, 256, 0, stream>>>(row, cnt);
    scan_bsum<<<SCAN_NB, 256, 0, stream>>>(cnt, bsum);
    scan_boff<<<1, 256, 0, stream>>>(bsum, boff, rowptr);
    scan_write<<<SCAN_NB, 256, 0, stream>>>(cnt, boff, rowptr, rowcur);
    scatter_edges<<<(NE + 255) / 256, 256, 0, stream>>>(row, col, vals, rowcur, epack);

    const int MT64 = (NN + 63) / 64;  // 782

    // layer 1: [50000,512] @ [512,256]
    gemm_bf16<256><<<MT64, 256, 0, stream>>>(Xb, Wt1, S, NN, 512);
    spmm_gather_bf16<256, true><<<(NN + 7) / 8, 256, 0, stream>>>(S, rowptr, epack, b1, Hb);
    // layer 2: [50000,256] @ [256,256]
    gemm_bf16<256><<<MT64, 256, 0, stream>>>(Hb, Wt2, S, NN, 256);
    spmm_gather_bf16<256, true><<<(NN + 7) / 8, 256, 0, stream>>>(S, rowptr, epack, b2, Hb);
    // layer 3: [50000,256] @ [256,128]
    gemm_bf16<128><<<MT64, 256, 0, stream>>>(Hb, Wt3, S, NN, 256);
    spmm_gather_bf16<128, true><<<(NN + 15) / 16, 256, 0, stream>>>(S, rowptr, epack, b3, Hb);
    // layer 4: [50000,128] @ [128,128]
    gemm_bf16<128><<<MT64, 256, 0, stream>>>(Hb, Wt4, S, NN, 128);
    spmm_gather_bf16<128, false><<<(NN + 15) / 16, 256, 0, stream>>>(S, rowptr, epack, b4, out);
}

// Round 11
// 373.321 us; speedup vs baseline: 1.1546x; 1.0131x over previous
//
#include <hip/hip_runtime.h>
#include <hip/hip_bf16.h>

#define NN 50000
#define NE 800000
#define LEAKY 0.25f
#define SCAN_NB ((NN + 255) / 256)   // 196

typedef __attribute__((ext_vector_type(8))) short bf16x8;
typedef __attribute__((ext_vector_type(8))) ushort u16x8;
typedef __attribute__((ext_vector_type(4))) float f32x4;
typedef unsigned long long ull;

#define AS1 const __attribute__((address_space(1))) void*
#define AS3 __attribute__((address_space(3))) void*

static __device__ __forceinline__ ushort f2bf(float f) {
    union { __hip_bfloat16 h; ushort u; } cv;
    cv.h = __float2bfloat16(f);
    return cv.u;
}
static __device__ __forceinline__ float bf2f(ushort u) {
    union { unsigned u; float f; } cv;
    cv.u = ((unsigned)u) << 16;
    return cv.f;
}

// ---------------- casts ----------------
__global__ void cast_bf16_x8(const float4* __restrict__ in, u16x8* __restrict__ out, int n8) {
    int i = blockIdx.x * blockDim.x + threadIdx.x;
    if (i >= n8) return;
    float4 v0 = in[i * 2];
    float4 v1 = in[i * 2 + 1];
    u16x8 o;
    o[0] = f2bf(v0.x); o[1] = f2bf(v0.y); o[2] = f2bf(v0.z); o[3] = f2bf(v0.w);
    o[4] = f2bf(v1.x); o[5] = f2bf(v1.y); o[6] = f2bf(v1.z); o[7] = f2bf(v1.w);
    out[i] = o;
}

// all 4 weight transposes in one launch
__global__ void cast_transpose_all(const float* __restrict__ W1, const float* __restrict__ W2,
                                   const float* __restrict__ W3, const float* __restrict__ W4,
                                   ushort* __restrict__ Wt1, ushort* __restrict__ Wt2,
                                   ushort* __restrict__ Wt3, ushort* __restrict__ Wt4) {
    int idx = blockIdx.x * blockDim.x + threadIdx.x;
    const float* W; ushort* Wt; int K, N, base;
    if (idx < 131072)      { W = W1; Wt = Wt1; K = 512; N = 256; base = 0; }
    else if (idx < 196608) { W = W2; Wt = Wt2; K = 256; N = 256; base = 131072; }
    else if (idx < 229376) { W = W3; Wt = Wt3; K = 256; N = 128; base = 196608; }
    else if (idx < 245760) { W = W4; Wt = Wt4; K = 128; N = 128; base = 229376; }
    else return;
    int l = idx - base;
    int k = l / N, n = l % N;
    Wt[n * K + k] = f2bf(W[l]);
}

// ---------------- bf16 MFMA GEMM: full-N, BM=64, 1-barrier double-buffered ----------------
// Grid = ceil(M/64) blocks of 256 threads (4 waves, 2x2). Wave computes 32 x BN/2.
template<int BN>
__global__ __launch_bounds__(256) void gemm_bf16(
    const ushort* __restrict__ A, const ushort* __restrict__ Bt,
    ushort* __restrict__ C, int M, int K)
{
    constexpr int NI = BN / 32;          // N-frags per wave (8 or 4)
    constexpr int BPASS = BN / 64;       // B staging passes (4 or 2)
    constexpr int ASZ = 64 * 32;         // ushorts per A buffer
    constexpr int BSZ = BN * 32;         // ushorts per B buffer
    __shared__ ushort As[2 * ASZ];
    __shared__ ushort Bs[2 * BSZ];
    const int tid  = threadIdx.x;
    const int lane = tid & 63;
    const int wid  = tid >> 6;
    const int wr = wid >> 1, wc = wid & 1;
    const int m0 = blockIdx.x * 64;

    int ar = m0 + (tid >> 2); if (ar >= M) ar = M - 1;
    const int ccol = (tid & 3) * 8;

    const ushort* gA = A + (size_t)ar * K + ccol;
    const ushort* gB[BPASS];
    #pragma unroll
    for (int p = 0; p < BPASS; ++p)
        gB[p] = Bt + (size_t)(p * 64 + (tid >> 2)) * K + ccol;

    const int fr = lane & 15;
    const int fq = lane >> 4;

    auto STAGE = [&](int buf, int k0) {
        char* lA = (char*)(As + buf * ASZ) + wid * 1024;
        char* lB = (char*)(Bs + buf * BSZ) + wid * 1024;
        __builtin_amdgcn_global_load_lds((AS1)(gA + k0), (AS3)lA, 16, 0, 0);
        #pragma unroll
        for (int p = 0; p < BPASS; ++p)
            __builtin_amdgcn_global_load_lds((AS1)(gB[p] + k0), (AS3)(lB + p * 4096), 16, 0, 0);
    };

    f32x4 acc[2][NI];
    #pragma unroll
    for (int i = 0; i < 2; ++i)
        #pragma unroll
        for (int j = 0; j < NI; ++j)
            acc[i][j] = {0.f, 0.f, 0.f, 0.f};

    STAGE(0, 0);
    const int nk = K >> 5;
    for (int t = 0; t < nk; ++t) {
        const int cur = t & 1;
        __syncthreads();                       // drains stage(cur); all waves done reading buf cur^1
        if (t + 1 < nk) STAGE(cur ^ 1, (t + 1) << 5);   // flies during MFMA below

        const ushort* fragA = As + cur * ASZ + (wr * 32 + fr) * 32 + fq * 8;
        const ushort* fragB = Bs + cur * BSZ + (wc * (BN / 2) + fr) * 32 + fq * 8;
        bf16x8 a[2], b[NI];
        #pragma unroll
        for (int mi = 0; mi < 2; ++mi) a[mi] = *(const bf16x8*)(fragA + mi * 16 * 32);
        #pragma unroll
        for (int ni = 0; ni < NI; ++ni) b[ni] = *(const bf16x8*)(fragB + ni * 16 * 32);
        #pragma unroll
        for (int mi = 0; mi < 2; ++mi)
            #pragma unroll
            for (int ni = 0; ni < NI; ++ni)
                acc[mi][ni] = __builtin_amdgcn_mfma_f32_16x16x32_bf16(a[mi], b[ni], acc[mi][ni], 0, 0, 0);
    }

    #pragma unroll
    for (int mi = 0; mi < 2; ++mi) {
        #pragma unroll
        for (int j = 0; j < 4; ++j) {
            int row = m0 + wr * 32 + mi * 16 + fq * 4 + j;
            if (row >= M) continue;
            #pragma unroll
            for (int ni = 0; ni < NI; ++ni) {
                int colg = wc * (BN / 2) + ni * 16 + fr;
                C[(size_t)row * BN + colg] = f2bf(acc[mi][ni][j]);
            }
        }
    }
}

// ---------------- CSR construction ----------------
__global__ void hist_rows(const int* __restrict__ row, int* __restrict__ cnt) {
    int e = blockIdx.x * blockDim.x + threadIdx.x;
    if (e < NE) atomicAdd(&cnt[row[e]], 1);
}

__global__ void scan_bsum(const int* __restrict__ cnt, int* __restrict__ bsum) {
    int i = blockIdx.x * 256 + threadIdx.x;
    int v = (i < NN) ? cnt[i] : 0;
    #pragma unroll
    for (int off = 32; off >= 1; off >>= 1) v += __shfl_down(v, off);
    __shared__ int ws[4];
    if ((threadIdx.x & 63) == 0) ws[threadIdx.x >> 6] = v;
    __syncthreads();
    if (threadIdx.x == 0) bsum[blockIdx.x] = ws[0] + ws[1] + ws[2] + ws[3];
}

__global__ void scan_boff(const int* __restrict__ bsum, int* __restrict__ boff,
                          int* __restrict__ rowptr) {
    __shared__ int s[256];
    int t = threadIdx.x;
    int v = (t < SCAN_NB) ? bsum[t] : 0;
    s[t] = v;
    __syncthreads();
    #pragma unroll
    for (int off = 1; off < 256; off <<= 1) {
        int u = (t >= off) ? s[t - off] : 0;
        __syncthreads();
        s[t] += u;
        __syncthreads();
    }
    if (t < SCAN_NB) boff[t] = s[t] - v;
    if (t == 255) rowptr[NN] = s[255];
}

__global__ void scan_write(const int* __restrict__ cnt, const int* __restrict__ boff,
                           int* __restrict__ rowptr, int* __restrict__ rowcur) {
    __shared__ int s[256];
    int b = blockIdx.x;
    int t = threadIdx.x;
    int i = b * 256 + t;
    int v = (i < NN) ? cnt[i] : 0;
    s[t] = v;
    __syncthreads();
    #pragma unroll
    for (int off = 1; off < 256; off <<= 1) {
        int u = (t >= off) ? s[t - off] : 0;
        __syncthreads();
        s[t] += u;
        __syncthreads();
    }
    if (i < NN) {
        int ex = boff[b] + s[t] - v;
        rowptr[i] = ex;
        rowcur[i] = ex;
    }
}

__global__ void scatter_edges(const int* __restrict__ row, const int* __restrict__ col,
                              const float* __restrict__ vals,
                              int* __restrict__ rowcur,
                              ull* __restrict__ epack) {
    int e = blockIdx.x * blockDim.x + threadIdx.x;
    if (e < NE) {
        int p = atomicAdd(&rowcur[row[e]], 1);
        ull pk = ((ull)__float_as_uint(vals[e]) << 32) | (unsigned)col[e];
        epack[p] = pk;
    }
}

// ---------------- SpMM gather (bf16 support) + bias + leakyReLU fused ----------------
template<int DIM, bool OUT_BF16>
__global__ __launch_bounds__(256) void spmm_gather_bf16(
    const ushort* __restrict__ support,
    const int* __restrict__ rowptr,
    const ull* __restrict__ epack,
    const float* __restrict__ bias,
    void* __restrict__ out) {
    constexpr int LPR = DIM / 8;        // lanes per row (32 or 16)
    constexpr int RPB = 256 / LPR;      // rows per block (8 or 16)
    int r = blockIdx.x * RPB + threadIdx.x / LPR;
    int lane = threadIdx.x % LPR;
    if (r >= NN) return;
    int s = rowptr[r], e = rowptr[r + 1];
    float acc0[8] = {}, acc1[8] = {};
    int i = s;
    for (; i + 3 < e; i += 4) {
        ull p0 = epack[i];
        ull p1 = epack[i + 1];
        ull p2 = epack[i + 2];
        ull p3 = epack[i + 3];
        u16x8 v0 = *((const u16x8*)(support + (size_t)(unsigned)p0 * DIM) + lane);
        u16x8 v1 = *((const u16x8*)(support + (size_t)(unsigned)p1 * DIM) + lane);
        u16x8 v2 = *((const u16x8*)(support + (size_t)(unsigned)p2 * DIM) + lane);
        u16x8 v3 = *((const u16x8*)(support + (size_t)(unsigned)p3 * DIM) + lane);
        float w0 = __uint_as_float((unsigned)(p0 >> 32));
        float w1 = __uint_as_float((unsigned)(p1 >> 32));
        float w2 = __uint_as_float((unsigned)(p2 >> 32));
        float w3 = __uint_as_float((unsigned)(p3 >> 32));
        #pragma unroll
        for (int j = 0; j < 8; ++j) acc0[j] += w0 * bf2f(v0[j]);
        #pragma unroll
        for (int j = 0; j < 8; ++j) acc1[j] += w1 * bf2f(v1[j]);
        #pragma unroll
        for (int j = 0; j < 8; ++j) acc0[j] += w2 * bf2f(v2[j]);
        #pragma unroll
        for (int j = 0; j < 8; ++j) acc1[j] += w3 * bf2f(v3[j]);
    }
    for (; i < e; ++i) {
        ull p0 = epack[i];
        float w0 = __uint_as_float((unsigned)(p0 >> 32));
        u16x8 v0 = *((const u16x8*)(support + (size_t)(unsigned)p0 * DIM) + lane);
        #pragma unroll
        for (int j = 0; j < 8; ++j) acc0[j] += w0 * bf2f(v0[j]);
    }
    const float4 bb0 = ((const float4*)bias)[lane * 2];
    const float4 bb1 = ((const float4*)bias)[lane * 2 + 1];
    float acc[8];
    #pragma unroll
    for (int j = 0; j < 8; ++j) acc[j] = acc0[j] + acc1[j];
    acc[0] += bb0.x; acc[1] += bb0.y; acc[2] += bb0.z; acc[3] += bb0.w;
    acc[4] += bb1.x; acc[5] += bb1.y; acc[6] += bb1.z; acc[7] += bb1.w;
    #pragma unroll
    for (int j = 0; j < 8; ++j) acc[j] = (acc[j] >= 0.f) ? acc[j] : LEAKY * acc[j];
    if (OUT_BF16) {
        ushort4 o0, o1;
        o0.x = f2bf(acc[0]); o0.y = f2bf(acc[1]); o0.z = f2bf(acc[2]); o0.w = f2bf(acc[3]);
        o1.x = f2bf(acc[4]); o1.y = f2bf(acc[5]); o1.z = f2bf(acc[6]); o1.w = f2bf(acc[7]);
        ((ushort4*)out)[(size_t)r * LPR * 2 + lane * 2]     = o0;
        ((ushort4*)out)[(size_t)r * LPR * 2 + lane * 2 + 1] = o1;
    } else {
        float4 f0 = {acc[0], acc[1], acc[2], acc[3]};
        float4 f1 = {acc[4], acc[5], acc[6], acc[7]};
        ((float4*)out)[(size_t)r * LPR * 2 + lane * 2]     = f0;
        ((float4*)out)[(size_t)r * LPR * 2 + lane * 2 + 1] = f1;
    }
}

extern "C" void kernel_launch(void* const* d_in, const int* in_sizes, int n_in,
                              void* d_out, int out_size, void* d_ws, size_t ws_size,
                              hipStream_t stream) {
    const float* x    = (const float*)d_in[0];
    const int*   row  = (const int*)d_in[1];
    const int*   col  = (const int*)d_in[2];
    const float* vals = (const float*)d_in[3];
    const float* W1 = (const float*)d_in[4];  const float* b1 = (const float*)d_in[5];
    const float* W2 = (const float*)d_in[6];  const float* b2 = (const float*)d_in[7];
    const float* W3 = (const float*)d_in[8];  const float* b3 = (const float*)d_in[9];
    const float* W4 = (const float*)d_in[10]; const float* b4 = (const float*)d_in[11];

    ushort* Xb = (ushort*)d_ws;
    ushort* Hb = Xb;
    ushort* S  = Xb + (size_t)NN * 512;
    ushort* Wt1 = S + (size_t)NN * 256;
    ushort* Wt2 = Wt1 + 512 * 256;
    ushort* Wt3 = Wt2 + 256 * 256;
    ushort* Wt4 = Wt3 + 256 * 128;
    int* cnt    = (int*)(Wt4 + 128 * 128);
    int* rowptr = cnt + NN;
    int* rowcur = rowptr + (NN + 1);
    int* pend   = rowcur + (NN + 1);
    ull* epack  = (ull*)pend;
    int* bsum   = (int*)(epack + NE);
    int* boff   = bsum + SCAN_NB;
    float* out  = (float*)d_out;

    // ---- casts ----
    {
        int n8 = NN * 512 / 8;
        cast_bf16_x8<<<(n8 + 255) / 256, 256, 0, stream>>>((const float4*)x, (u16x8*)Xb, n8);
        cast_transpose_all<<<(245760 + 255) / 256, 256, 0, stream>>>(W1, W2, W3, W4, Wt1, Wt2, Wt3, Wt4);
    }

    // ---- build CSR ----
    hipMemsetAsync(cnt, 0, NN * sizeof(int), stream);
    hist_rows<<<(NE + 255) / 256, 256, 0, stream>>>(row, cnt);
    scan_bsum<<<SCAN_NB, 256, 0, stream>>>(cnt, bsum);
    scan_boff<<<1, 256, 0, stream>>>(bsum, boff, rowptr);
    scan_write<<<SCAN_NB, 256, 0, stream>>>(cnt, boff, rowptr, rowcur);
    scatter_edges<<<(NE + 255) / 256, 256, 0, stream>>>(row, col, vals, rowcur, epack);

    const int MT64 = (NN + 63) / 64;  // 782

    // layer 1: [50000,512] @ [512,256]
    gemm_bf16<256><<<MT64, 256, 0, stream>>>(Xb, Wt1, S, NN, 512);
    spmm_gather_bf16<256, true><<<(NN + 7) / 8, 256, 0, stream>>>(S, rowptr, epack, b1, Hb);
    // layer 2: [50000,256] @ [256,256]
    gemm_bf16<256><<<MT64, 256, 0, stream>>>(Hb, Wt2, S, NN, 256);
    spmm_gather_bf16<256, true><<<(NN + 7) / 8, 256, 0, stream>>>(S, rowptr, epack, b2, Hb);
    // layer 3: [50000,256] @ [256,128]
    gemm_bf16<128><<<MT64, 256, 0, stream>>>(Hb, Wt3, S, NN, 256);
    spmm_gather_bf16<128, true><<<(NN + 15) / 16, 256, 0, stream>>>(S, rowptr, epack, b3, Hb);
    // layer 4: [50000,128] @ [128,128]
    gemm_bf16<128><<<MT64, 256, 0, stream>>>(Hb, Wt4, S, NN, 128);
    spmm_gather_bf16<128, false><<<(NN + 15) / 16, 256, 0, stream>>>(S, rowptr, epack, b4, out);
}